// Round 14
// baseline (745.697 us; speedup 1.0000x reference)
//
#include <hip/hip_runtime.h>

#define DHID 64
#define DIN 6
#define SDEG 16
#define BSH 6                 // bucket = dst >> 6 (64 nodes/bucket)
#define NBMAX 2048            // LDS histogram capacity (NB = 1563 for N=100k)
#define NGRP 128              // radix groups (WGs); chunk = E/NGRP ~ 12.5k edges

static __device__ __forceinline__ float rlane(float v, int k) {
  return __uint_as_float(__builtin_amdgcn_readlane(__float_as_uint(v), k));
}
static __device__ __forceinline__ unsigned short f2bf(float f) {  // RNE pack
  unsigned u = __float_as_uint(f);
  return (unsigned short)((u + 0x7fff + ((u >> 16) & 1)) >> 16);
}
static __device__ __forceinline__ float bf2f(unsigned short u) {
  return __uint_as_float((unsigned)u << 16);
}

// ---- CSR build: per-WG-histogram radix sort (no global atomics) ------------

__global__ __launch_bounds__(256) void k_hist2(const int* __restrict__ dst,
                                               int* __restrict__ hist, int E, int NB) {
  __shared__ int h[NBMAX];
  int g = blockIdx.x;
  for (int i = threadIdx.x; i < NB; i += 256) h[i] = 0;
  __syncthreads();
  int chunk = (E + NGRP - 1) / NGRP;
  int e0 = g * chunk, e1 = min(E, e0 + chunk);
  for (int e = e0 + threadIdx.x; e < e1; e += 256)
    atomicAdd(&h[dst[e] >> BSH], 1);
  __syncthreads();
  for (int i = threadIdx.x; i < NB; i += 256)
    hist[(size_t)g * NB + i] = h[i];
}

__global__ __launch_bounds__(256) void k_scan2a(int* __restrict__ hist,
                                                int* __restrict__ colsum, int NB) {
  int b = blockIdx.x * 256 + threadIdx.x;
  if (b >= NB) return;
  int s = 0;
  for (int g = 0; g < NGRP; ++g) {
    size_t idx = (size_t)g * NB + b;
    int v = hist[idx];
    hist[idx] = s;
    s += v;
  }
  colsum[b] = s;
}

__global__ void k_scan2b(const int* __restrict__ colsum, int* __restrict__ bbase,
                         int NB) {
  int t = threadIdx.x;  // 64 threads
  int run = 0;
  for (int base = 0; base < NB; base += 64) {
    int i = base + t;
    int d = (i < NB) ? colsum[i] : 0;
    int v = d;
#pragma unroll
    for (int off = 1; off < 64; off <<= 1) {
      int u = __shfl_up(v, off);
      if (t >= off) v += u;
    }
    if (i < NB) bbase[i] = run + v - d;
    run += __shfl(v, 63);
  }
  if (t == 0) bbase[NB] = run;
}

__global__ __launch_bounds__(256) void k_scatter2(
    const int* __restrict__ src, const int* __restrict__ dst,
    const int* __restrict__ hist, const int* __restrict__ bbase,
    int* __restrict__ ebuf, const int* __restrict__ selfp,
    int* __restrict__ selfcnt, int* __restrict__ selflist, int E, int NB) {
  __shared__ int cur[NBMAX];
  int g = blockIdx.x;
  for (int i = threadIdx.x; i < NB; i += 256)
    cur[i] = hist[(size_t)g * NB + i] + bbase[i];
  __syncthreads();
  int self = *selfp;
  int chunk = (E + NGRP - 1) / NGRP;
  int e0 = g * chunk, e1 = min(E, e0 + chunk);
  for (int e = e0 + threadIdx.x; e < e1; e += 256) {
    int s = src[e], d = dst[e];
    int pos = atomicAdd(&cur[d >> BSH], 1);     // LDS atomic
    ebuf[pos] = (s << BSH) | (d & 63);
    if (s == self) {
      int i = atomicAdd(selfcnt, 1);
      if (i < SDEG) selflist[i] = e;
    }
  }
}

__global__ __launch_bounds__(256) void k_bfill(
    const int* __restrict__ ebuf, const int* __restrict__ bbase,
    int* __restrict__ rowptr, int* __restrict__ deg, int* __restrict__ col,
    int N) {
  __shared__ int cnt[64], cur[64];
  int b = blockIdx.x;
  int t = threadIdx.x;  // 256
  if (t < 64) cnt[t] = 0;
  __syncthreads();
  int lo = bbase[b], hi = bbase[b + 1];
  for (int i = lo + t; i < hi; i += 256) atomicAdd(&cnt[ebuf[i] & 63], 1);
  __syncthreads();
  if (t < 64) {
    int c = cnt[t];
    int v = c;
#pragma unroll
    for (int off = 1; off < 64; off <<= 1) {
      int u = __shfl_up(v, off);
      if (t >= off) v += u;
    }
    int start = lo + v - c;
    int node = (b << BSH) + t;
    if (node < N) { rowptr[node] = start; deg[node] = c; }
    cur[t] = start;
  }
  __syncthreads();
  for (int i = lo + t; i < hi; i += 256) {
    int p = ebuf[i];
    int pos = atomicAdd(&cur[p & 63], 1);
    col[pos] = p >> BSH;
  }
}

// ---- Layer 0: x[N,6] -> h[N,64] bf16, ReLU ---------------------------------

__global__ __launch_bounds__(256) void k_layer0(
    const float* __restrict__ x, const int* __restrict__ rowptr,
    const int* __restrict__ deg, const int* __restrict__ col,
    const float* __restrict__ W0l, const float* __restrict__ W0r,
    const float* __restrict__ b0, unsigned short* __restrict__ hbout, int N) {
  int lane = threadIdx.x & 63;
  int wid = blockIdx.x * (blockDim.x >> 6) + (threadIdx.x >> 6);
  int nw = gridDim.x * (blockDim.x >> 6);
  float w0l[DIN], w0r[DIN];
#pragma unroll
  for (int k = 0; k < DIN; ++k) {
    w0l[k] = W0l[k * DHID + lane];
    w0r[k] = W0r[k * DHID + lane];
  }
  float bv = b0[lane];
  int d6 = (lane < DIN) ? lane : 0;
  for (int node = wid; node < N; node += nw) {
    int start = rowptr[node], cnt = deg[node];
    float a0 = 0.f, a1 = 0.f, a2 = 0.f, a3 = 0.f;
    float a4 = 0.f, a5 = 0.f, a6 = 0.f, a7 = 0.f;
    int e = 0;
    for (; e + 8 <= cnt; e += 8) {           // 8 independent gather chains
      int s0 = col[start + e + 0], s1 = col[start + e + 1];
      int s2 = col[start + e + 2], s3 = col[start + e + 3];
      int s4 = col[start + e + 4], s5 = col[start + e + 5];
      int s6 = col[start + e + 6], s7 = col[start + e + 7];
      a0 += x[s0 * DIN + d6];
      a1 += x[s1 * DIN + d6];
      a2 += x[s2 * DIN + d6];
      a3 += x[s3 * DIN + d6];
      a4 += x[s4 * DIN + d6];
      a5 += x[s5 * DIN + d6];
      a6 += x[s6 * DIN + d6];
      a7 += x[s7 * DIN + d6];
    }
    for (; e < cnt; ++e) a0 += x[col[start + e] * DIN + d6];
    float acc = ((a0 + a1) + (a2 + a3)) + ((a4 + a5) + (a6 + a7));
    float mean = acc / fmaxf((float)cnt, 1.0f);
    float xi = x[node * DIN + d6];
    float outv = bv;
#pragma unroll
    for (int k = 0; k < DIN; ++k) {
      outv = fmaf(rlane(mean, k), w0l[k], outv);
      outv = fmaf(rlane(xi, k), w0r[k], outv);
    }
    outv = fmaxf(outv, 0.f);
    hbout[(size_t)node * DHID + lane] = f2bf(outv);
  }
}

// ---- Fused layer: mean-aggregate + (mean@Wl + h@Wr + b) in one kernel ------
// Wave-per-node. Lane j holds column j of Wl/Wr in 128 VGPRs (guaranteed
// resident by __launch_bounds__(256,2): 256-VGPR budget — R1's failure was
// the default ~80-VGPR budget rematerializing these). 16-deep bf16 gather
// for MLP; matvec via 64 unrolled readlane broadcasts (1 SGPR operand/fma).
// Grid 512 blocks = 2 blocks/CU exactly (2 waves/SIMD cap), persistent.

__global__ __launch_bounds__(256, 2) void k_flayer(
    const unsigned short* __restrict__ hb, const int* __restrict__ rowptr,
    const int* __restrict__ deg, const int* __restrict__ col,
    const float* __restrict__ Wl, const float* __restrict__ Wr,
    const float* __restrict__ b, unsigned short* __restrict__ hbout,
    float* __restrict__ hfout, int N, int do_relu) {
  int lane = threadIdx.x & 63;
  int wid = blockIdx.x * (blockDim.x >> 6) + (threadIdx.x >> 6);
  int nw = gridDim.x * (blockDim.x >> 6);
  float wl[DHID], wr[DHID];
#pragma unroll
  for (int k = 0; k < DHID; ++k) wl[k] = Wl[k * DHID + lane];
#pragma unroll
  for (int k = 0; k < DHID; ++k) wr[k] = Wr[k * DHID + lane];
  float bv = b[lane];

  for (int node = wid; node < N; node += nw) {
    int start = rowptr[node], cnt = deg[node];
    float a0 = 0.f, a1 = 0.f, a2 = 0.f, a3 = 0.f;
    float a4 = 0.f, a5 = 0.f, a6 = 0.f, a7 = 0.f;
    float a8 = 0.f, a9 = 0.f, aA = 0.f, aB = 0.f;
    float aC = 0.f, aD = 0.f, aE = 0.f, aF = 0.f;
    int e = 0;
    for (; e + 16 <= cnt; e += 16) {        // 16 outstanding gathers
      int s0 = col[start + e + 0], s1 = col[start + e + 1];
      int s2 = col[start + e + 2], s3 = col[start + e + 3];
      int s4 = col[start + e + 4], s5 = col[start + e + 5];
      int s6 = col[start + e + 6], s7 = col[start + e + 7];
      int s8 = col[start + e + 8], s9 = col[start + e + 9];
      int sA = col[start + e + 10], sB = col[start + e + 11];
      int sC = col[start + e + 12], sD = col[start + e + 13];
      int sE = col[start + e + 14], sF = col[start + e + 15];
      a0 += bf2f(hb[(size_t)s0 * DHID + lane]);
      a1 += bf2f(hb[(size_t)s1 * DHID + lane]);
      a2 += bf2f(hb[(size_t)s2 * DHID + lane]);
      a3 += bf2f(hb[(size_t)s3 * DHID + lane]);
      a4 += bf2f(hb[(size_t)s4 * DHID + lane]);
      a5 += bf2f(hb[(size_t)s5 * DHID + lane]);
      a6 += bf2f(hb[(size_t)s6 * DHID + lane]);
      a7 += bf2f(hb[(size_t)s7 * DHID + lane]);
      a8 += bf2f(hb[(size_t)s8 * DHID + lane]);
      a9 += bf2f(hb[(size_t)s9 * DHID + lane]);
      aA += bf2f(hb[(size_t)sA * DHID + lane]);
      aB += bf2f(hb[(size_t)sB * DHID + lane]);
      aC += bf2f(hb[(size_t)sC * DHID + lane]);
      aD += bf2f(hb[(size_t)sD * DHID + lane]);
      aE += bf2f(hb[(size_t)sE * DHID + lane]);
      aF += bf2f(hb[(size_t)sF * DHID + lane]);
    }
    for (; e + 4 <= cnt; e += 4) {
      int s0 = col[start + e + 0], s1 = col[start + e + 1];
      int s2 = col[start + e + 2], s3 = col[start + e + 3];
      a0 += bf2f(hb[(size_t)s0 * DHID + lane]);
      a1 += bf2f(hb[(size_t)s1 * DHID + lane]);
      a2 += bf2f(hb[(size_t)s2 * DHID + lane]);
      a3 += bf2f(hb[(size_t)s3 * DHID + lane]);
    }
    for (; e < cnt; ++e) a0 += bf2f(hb[(size_t)col[start + e] * DHID + lane]);
    float s = (((a0 + a1) + (a2 + a3)) + ((a4 + a5) + (a6 + a7))) +
              (((a8 + a9) + (aA + aB)) + ((aC + aD) + (aE + aF)));
    float mean = s / fmaxf((float)cnt, 1.0f);
    float hi = bf2f(hb[(size_t)node * DHID + lane]);

    float outv = bv;
#pragma unroll
    for (int k = 0; k < DHID; ++k) {
      outv = fmaf(rlane(mean, k), wl[k], outv);
      outv = fmaf(rlane(hi, k), wr[k], outv);
    }
    if (do_relu) outv = fmaxf(outv, 0.f);
    if (hbout) hbout[(size_t)node * DHID + lane] = f2bf(outv);
    if (hfout) hfout[(size_t)node * DHID + lane] = outv;
  }
}

// ---- Head: sort self-edges, logits, value, neighbors -----------------------

__global__ void k_head(const float* __restrict__ h, const int* __restrict__ dst,
                       const int* __restrict__ selfp, const int* __restrict__ selflist,
                       const int* __restrict__ selfcnt, const float* __restrict__ Wlog,
                       const float* __restrict__ blog, const float* __restrict__ Wval,
                       const float* __restrict__ bval, float* __restrict__ out) {
  __shared__ int sorted[SDEG];
  __shared__ int nbr[SDEG];
  int t = threadIdx.x;  // block = 64 threads (1 wave)
  int self = *selfp;
  if (t == 0) {
    int c = *selfcnt;
    if (c > SDEG) c = SDEG;
    int tmp[SDEG];
    for (int j = 0; j < SDEG; ++j) tmp[j] = (j < c) ? selflist[j] : 0;
    for (int a = 1; a < c; ++a) {
      int v = tmp[a];
      int bq = a - 1;
      while (bq >= 0 && tmp[bq] > v) { tmp[bq + 1] = tmp[bq]; --bq; }
      tmp[bq + 1] = v;
    }
    for (int j = 0; j < SDEG; ++j) sorted[j] = tmp[j];
  }
  __syncthreads();
  if (t < SDEG) nbr[t] = dst[sorted[t]];
  __syncthreads();

  int r = t >> 2, p = t & 3;
  float part = 0.f;
  for (int k = p * 32; k < p * 32 + 32; ++k) {
    float ev = (k < DHID) ? h[self * DHID + k] : h[nbr[r] * DHID + (k - DHID)];
    part += ev * Wlog[k];
  }
  part += __shfl_xor(part, 1);
  part += __shfl_xor(part, 2);
  if (p == 0) out[r] = part + blog[0];

  float pv = h[self * DHID + t] * Wval[t];
#pragma unroll
  for (int off = 32; off; off >>= 1) pv += __shfl_xor(pv, off);
  if (t == 0) out[SDEG] = pv + bval[0];

  if (t < SDEG) out[SDEG + 1 + t] = (float)nbr[t];
}

// ---- launcher --------------------------------------------------------------

extern "C" void kernel_launch(void* const* d_in, const int* in_sizes, int n_in,
                              void* d_out, int out_size, void* d_ws, size_t ws_size,
                              hipStream_t stream) {
  const float* x    = (const float*)d_in[0];
  const int*   ei   = (const int*)d_in[1];
  const int*   selfp= (const int*)d_in[2];
  const float* W0l  = (const float*)d_in[3];
  const float* W0r  = (const float*)d_in[4];
  const float* b0   = (const float*)d_in[5];
  const float* Wl   = (const float*)d_in[6];
  const float* Wr   = (const float*)d_in[7];
  const float* bb   = (const float*)d_in[8];
  const float* Wlog = (const float*)d_in[9];
  const float* blog = (const float*)d_in[10];
  const float* Wval = (const float*)d_in[11];
  const float* bval = (const float*)d_in[12];
  float* out = (float*)d_out;

  int N = in_sizes[0] / DIN;
  int E = in_sizes[1] / 2;
  int NB = (N + 63) >> BSH;
  const int* src = ei;
  const int* dstp = ei + E;

  size_t off = 0;
  auto alloc = [&](size_t bytes) {
    void* p = (char*)d_ws + off;
    off += (bytes + 255) & ~(size_t)255;
    return p;
  };
  int* meta    = (int*)alloc(64 * 4);            // [0]=selfcnt [1..16]=selflist
  int* hist    = (int*)alloc((size_t)NGRP * NB * 4);
  int* bbase   = (int*)alloc((size_t)(NB + 1) * 4);
  int* colsum  = (int*)alloc((size_t)NB * 4);
  int* ebuf    = (int*)alloc((size_t)E * 4);
  int* deg     = (int*)alloc((size_t)N * 4);
  int* rowptr  = (int*)alloc((size_t)N * 4);
  int* col     = (int*)alloc((size_t)E * 4);
  float* hF    = (float*)alloc((size_t)N * DHID * 4);          // final f32 h
  unsigned short* hb0 = (unsigned short*)alloc((size_t)N * DHID * 2);
  unsigned short* hb1 = (unsigned short*)alloc((size_t)N * DHID * 2);
  unsigned short* hb2 = (unsigned short*)alloc((size_t)N * DHID * 2);
  int* selfcnt  = meta + 0;
  int* selflist = meta + 1;

  hipMemsetAsync(meta, 0, 64 * 4, stream);

  const int TB = 256;
  k_hist2<<<NGRP, TB, 0, stream>>>(dstp, hist, E, NB);
  k_scan2a<<<(NB + TB - 1) / TB, TB, 0, stream>>>(hist, colsum, NB);
  k_scan2b<<<1, 64, 0, stream>>>(colsum, bbase, NB);
  k_scatter2<<<NGRP, TB, 0, stream>>>(src, dstp, hist, bbase, ebuf, selfp,
                                      selfcnt, selflist, E, NB);
  k_bfill<<<NB, TB, 0, stream>>>(ebuf, bbase, rowptr, deg, col, N);

  k_layer0<<<2048, 256, 0, stream>>>(x, rowptr, deg, col, W0l, W0r, b0, hb0, N);

  // fused layers: 512 blocks = 2 blocks/CU (2 waves/SIMD), persistent waves
  k_flayer<<<512, 256, 0, stream>>>(hb0, rowptr, deg, col, Wl + 0 * 4096,
                                    Wr + 0 * 4096, bb + 0 * 64, hb1,
                                    (float*)nullptr, N, 1);
  k_flayer<<<512, 256, 0, stream>>>(hb1, rowptr, deg, col, Wl + 1 * 4096,
                                    Wr + 1 * 4096, bb + 1 * 64, hb2,
                                    (float*)nullptr, N, 1);
  k_flayer<<<512, 256, 0, stream>>>(hb2, rowptr, deg, col, Wl + 2 * 4096,
                                    Wr + 2 * 4096, bb + 2 * 64,
                                    (unsigned short*)nullptr, hF, N, 0);

  k_head<<<1, 64, 0, stream>>>(hF, dstp, selfp, selflist, selfcnt, Wlog, blog,
                               Wval, bval, out);
}

// Round 15
// 479.208 us; speedup vs baseline: 1.5561x; 1.5561x over previous
//
#include <hip/hip_runtime.h>

#define DHID 64
#define DIN 6
#define SDEG 16
#define BSH 6                 // bucket = dst >> 6 (64 nodes/bucket)
#define NBMAX 2048            // LDS histogram capacity (NB = 1563 for N=100k)
#define NGRP 128              // radix groups (WGs); chunk = E/NGRP ~ 12.5k edges

static __device__ __forceinline__ float rlane(float v, int k) {
  return __uint_as_float(__builtin_amdgcn_readlane(__float_as_uint(v), k));
}
static __device__ __forceinline__ unsigned short f2bf(float f) {  // RNE pack
  unsigned u = __float_as_uint(f);
  return (unsigned short)((u + 0x7fff + ((u >> 16) & 1)) >> 16);
}
static __device__ __forceinline__ float bf2f(unsigned short u) {
  return __uint_as_float((unsigned)u << 16);
}
static __device__ __forceinline__ float bflo(unsigned u) {  // low bf16 of a u32
  return __uint_as_float(u << 16);
}
static __device__ __forceinline__ float bfhi(unsigned u) {  // high bf16 of a u32
  return __uint_as_float(u & 0xffff0000u);
}

// ---- CSR build: per-WG-histogram radix sort (no global atomics) ------------

__global__ __launch_bounds__(256) void k_hist2(const int* __restrict__ dst,
                                               int* __restrict__ hist, int E, int NB) {
  __shared__ int h[NBMAX];
  int g = blockIdx.x;
  for (int i = threadIdx.x; i < NB; i += 256) h[i] = 0;
  __syncthreads();
  int chunk = (E + NGRP - 1) / NGRP;
  int e0 = g * chunk, e1 = min(E, e0 + chunk);
  for (int e = e0 + threadIdx.x; e < e1; e += 256)
    atomicAdd(&h[dst[e] >> BSH], 1);
  __syncthreads();
  for (int i = threadIdx.x; i < NB; i += 256)
    hist[(size_t)g * NB + i] = h[i];
}

__global__ __launch_bounds__(256) void k_scan2a(int* __restrict__ hist,
                                                int* __restrict__ colsum, int NB) {
  int b = blockIdx.x * 256 + threadIdx.x;
  if (b >= NB) return;
  int s = 0;
  for (int g = 0; g < NGRP; ++g) {
    size_t idx = (size_t)g * NB + b;
    int v = hist[idx];
    hist[idx] = s;
    s += v;
  }
  colsum[b] = s;
}

__global__ void k_scan2b(const int* __restrict__ colsum, int* __restrict__ bbase,
                         int NB) {
  int t = threadIdx.x;  // 64 threads
  int run = 0;
  for (int base = 0; base < NB; base += 64) {
    int i = base + t;
    int d = (i < NB) ? colsum[i] : 0;
    int v = d;
#pragma unroll
    for (int off = 1; off < 64; off <<= 1) {
      int u = __shfl_up(v, off);
      if (t >= off) v += u;
    }
    if (i < NB) bbase[i] = run + v - d;
    run += __shfl(v, 63);
  }
  if (t == 0) bbase[NB] = run;
}

__global__ __launch_bounds__(256) void k_scatter2(
    const int* __restrict__ src, const int* __restrict__ dst,
    const int* __restrict__ hist, const int* __restrict__ bbase,
    int* __restrict__ ebuf, const int* __restrict__ selfp,
    int* __restrict__ selfcnt, int* __restrict__ selflist, int E, int NB) {
  __shared__ int cur[NBMAX];
  int g = blockIdx.x;
  for (int i = threadIdx.x; i < NB; i += 256)
    cur[i] = hist[(size_t)g * NB + i] + bbase[i];
  __syncthreads();
  int self = *selfp;
  int chunk = (E + NGRP - 1) / NGRP;
  int e0 = g * chunk, e1 = min(E, e0 + chunk);
  for (int e = e0 + threadIdx.x; e < e1; e += 256) {
    int s = src[e], d = dst[e];
    int pos = atomicAdd(&cur[d >> BSH], 1);     // LDS atomic
    ebuf[pos] = (s << BSH) | (d & 63);
    if (s == self) {
      int i = atomicAdd(selfcnt, 1);
      if (i < SDEG) selflist[i] = e;
    }
  }
}

__global__ __launch_bounds__(256) void k_bfill(
    const int* __restrict__ ebuf, const int* __restrict__ bbase,
    int* __restrict__ rowptr, int* __restrict__ deg, int* __restrict__ col,
    int N) {
  __shared__ int cnt[64], cur[64];
  int b = blockIdx.x;
  int t = threadIdx.x;  // 256
  if (t < 64) cnt[t] = 0;
  __syncthreads();
  int lo = bbase[b], hi = bbase[b + 1];
  for (int i = lo + t; i < hi; i += 256) atomicAdd(&cnt[ebuf[i] & 63], 1);
  __syncthreads();
  if (t < 64) {
    int c = cnt[t];
    int v = c;
#pragma unroll
    for (int off = 1; off < 64; off <<= 1) {
      int u = __shfl_up(v, off);
      if (t >= off) v += u;
    }
    int start = lo + v - c;
    int node = (b << BSH) + t;
    if (node < N) { rowptr[node] = start; deg[node] = c; }
    cur[t] = start;
  }
  __syncthreads();
  for (int i = lo + t; i < hi; i += 256) {
    int p = ebuf[i];
    int pos = atomicAdd(&cur[p & 63], 1);
    col[pos] = p >> BSH;
  }
}

// ---- Layer 0: x[N,6] -> h[N,64] bf16, ReLU ---------------------------------

__global__ __launch_bounds__(256) void k_layer0(
    const float* __restrict__ x, const int* __restrict__ rowptr,
    const int* __restrict__ deg, const int* __restrict__ col,
    const float* __restrict__ W0l, const float* __restrict__ W0r,
    const float* __restrict__ b0, unsigned short* __restrict__ hbout, int N) {
  int lane = threadIdx.x & 63;
  int wid = blockIdx.x * (blockDim.x >> 6) + (threadIdx.x >> 6);
  int nw = gridDim.x * (blockDim.x >> 6);
  float w0l[DIN], w0r[DIN];
#pragma unroll
  for (int k = 0; k < DIN; ++k) {
    w0l[k] = W0l[k * DHID + lane];
    w0r[k] = W0r[k * DHID + lane];
  }
  float bv = b0[lane];
  int d6 = (lane < DIN) ? lane : 0;
  for (int node = wid; node < N; node += nw) {
    int start = rowptr[node], cnt = deg[node];
    float a0 = 0.f, a1 = 0.f, a2 = 0.f, a3 = 0.f;
    float a4 = 0.f, a5 = 0.f, a6 = 0.f, a7 = 0.f;
    int e = 0;
    for (; e + 8 <= cnt; e += 8) {           // 8 independent gather chains
      int s0 = col[start + e + 0], s1 = col[start + e + 1];
      int s2 = col[start + e + 2], s3 = col[start + e + 3];
      int s4 = col[start + e + 4], s5 = col[start + e + 5];
      int s6 = col[start + e + 6], s7 = col[start + e + 7];
      a0 += x[s0 * DIN + d6];
      a1 += x[s1 * DIN + d6];
      a2 += x[s2 * DIN + d6];
      a3 += x[s3 * DIN + d6];
      a4 += x[s4 * DIN + d6];
      a5 += x[s5 * DIN + d6];
      a6 += x[s6 * DIN + d6];
      a7 += x[s7 * DIN + d6];
    }
    for (; e < cnt; ++e) a0 += x[col[start + e] * DIN + d6];
    float acc = ((a0 + a1) + (a2 + a3)) + ((a4 + a5) + (a6 + a7));
    float mean = acc / fmaxf((float)cnt, 1.0f);
    float xi = x[node * DIN + d6];
    float outv = bv;
#pragma unroll
    for (int k = 0; k < DIN; ++k) {
      outv = fmaf(rlane(mean, k), w0l[k], outv);
      outv = fmaf(rlane(xi, k), w0r[k], outv);
    }
    outv = fmaxf(outv, 0.f);
    hbout[(size_t)node * DHID + lane] = f2bf(outv);
  }
}

// ---- Aggregation, dual-edge: 2 edges per load instruction ------------------
// Lanes 0-31 handle even-slot edges, lanes 32-63 odd-slot. Each lane loads a
// dword = 2 bf16 dims (2*l32, 2*l32+1) of its edge's row. Halves the load
// instruction count and address math vs 1-edge-per-wave. Cross-half combine
// via shfl_xor(32); lanes 0-31 write packed dwords (same meanb layout).

__global__ __launch_bounds__(256) void k_agg(
    const unsigned short* __restrict__ hb, const int* __restrict__ rowptr,
    const int* __restrict__ deg, const int* __restrict__ col,
    unsigned short* __restrict__ meanb, int N) {
  int lane = threadIdx.x & 63;
  int half = lane >> 5;          // which edge of each pair
  int l32 = lane & 31;           // dword index within row (dims 2*l32, 2*l32+1)
  const unsigned* hw = (const unsigned*)hb;   // 32 dwords per 64-dim bf16 row
  int wid = blockIdx.x * (blockDim.x >> 6) + (threadIdx.x >> 6);
  int nw = gridDim.x * (blockDim.x >> 6);
  for (int node = wid; node < N; node += nw) {
    int start = rowptr[node], cnt = deg[node];
    float p0 = 0.f, q0 = 0.f, p1 = 0.f, q1 = 0.f;
    float p2 = 0.f, q2 = 0.f, p3 = 0.f, q3 = 0.f;
    int e = 0;
    for (; e + 8 <= cnt; e += 8) {            // 4 loads cover 8 edges
      int s0 = col[start + e + 0 + half];
      int s1 = col[start + e + 2 + half];
      int s2 = col[start + e + 4 + half];
      int s3 = col[start + e + 6 + half];
      unsigned u0 = hw[(size_t)s0 * 32 + l32];
      unsigned u1 = hw[(size_t)s1 * 32 + l32];
      unsigned u2 = hw[(size_t)s2 * 32 + l32];
      unsigned u3 = hw[(size_t)s3 * 32 + l32];
      p0 += bflo(u0); q0 += bfhi(u0);
      p1 += bflo(u1); q1 += bfhi(u1);
      p2 += bflo(u2); q2 += bfhi(u2);
      p3 += bflo(u3); q3 += bfhi(u3);
    }
    for (; e + 2 <= cnt; e += 2) {
      int s = col[start + e + half];
      unsigned u = hw[(size_t)s * 32 + l32];
      p0 += bflo(u); q0 += bfhi(u);
    }
    if (e < cnt && half == 0) {               // odd remainder: half 0 only
      int s = col[start + e];
      unsigned u = hw[(size_t)s * 32 + l32];
      p0 += bflo(u); q0 += bfhi(u);
    }
    float sp = (p0 + p1) + (p2 + p3);
    float sq = (q0 + q1) + (q2 + q3);
    sp += __shfl_xor(sp, 32);
    sq += __shfl_xor(sq, 32);
    if (half == 0) {
      float inv = 1.0f / fmaxf((float)cnt, 1.0f);
      unsigned lo = (unsigned)f2bf(sp * inv);
      unsigned hi = (unsigned)f2bf(sq * inv);
      ((unsigned*)meanb)[(size_t)node * 32 + l32] = lo | (hi << 16);
    }
  }
}

// ---- Transform: out = mean@Wl + h@Wr + b -----------------------------------
// Single pass, acc[64] resident (launch_bounds(256,2)); bf16 inputs.

__global__ __launch_bounds__(256, 2) void k_mm(
    const unsigned short* __restrict__ meanb,
    const unsigned short* __restrict__ hinb,
    const float* __restrict__ Wl, const float* __restrict__ Wr,
    const float* __restrict__ b, float* __restrict__ hout,
    unsigned short* __restrict__ hbout, int N, int do_relu) {
  __shared__ float4 sW[2064];  // [0..1023]=Wl rows, [1024..2047]=Wr, [2048..2063]=b
  int t = threadIdx.x;
  const float4* wl4 = (const float4*)Wl;
  const float4* wr4 = (const float4*)Wr;
  for (int i = t; i < 1024; i += 256) sW[i] = wl4[i];
  for (int i = t; i < 1024; i += 256) sW[1024 + i] = wr4[i];
  if (t < 16) sW[2048 + t] = ((const float4*)b)[t];
  __syncthreads();

  int node = blockIdx.x * 256 + t;
  if (node >= N) return;

  const uint4* m4 = (const uint4*)(meanb + (size_t)node * DHID);  // 8 bf16/uint4
  const uint4* h4 = (const uint4*)(hinb + (size_t)node * DHID);

  float acc[DHID];
#pragma unroll
  for (int jc = 0; jc < 16; ++jc) {
    float4 bv = sW[2048 + jc];
    acc[jc * 4 + 0] = bv.x; acc[jc * 4 + 1] = bv.y;
    acc[jc * 4 + 2] = bv.z; acc[jc * 4 + 3] = bv.w;
  }

  for (int kc = 0; kc < 8; ++kc) {     // 8 k-values per iteration
    uint4 mv = m4[kc];
    uint4 hv = h4[kc];
    float am[8], ah[8];
    am[0] = bflo(mv.x); am[1] = bfhi(mv.x);
    am[2] = bflo(mv.y); am[3] = bfhi(mv.y);
    am[4] = bflo(mv.z); am[5] = bfhi(mv.z);
    am[6] = bflo(mv.w); am[7] = bfhi(mv.w);
    ah[0] = bflo(hv.x); ah[1] = bfhi(hv.x);
    ah[2] = bflo(hv.y); ah[3] = bfhi(hv.y);
    ah[4] = bflo(hv.z); ah[5] = bfhi(hv.z);
    ah[6] = bflo(hv.w); ah[7] = bfhi(hv.w);
#pragma unroll
    for (int kk = 0; kk < 8; ++kk) {
      int k = kc * 8 + kk;
      float a = am[kk], hh = ah[kk];
#pragma unroll
      for (int jc = 0; jc < 16; ++jc) {
        float4 wlv = sW[k * 16 + jc];
        float4 wrv = sW[1024 + k * 16 + jc];
        acc[jc * 4 + 0] = fmaf(a, wlv.x, fmaf(hh, wrv.x, acc[jc * 4 + 0]));
        acc[jc * 4 + 1] = fmaf(a, wlv.y, fmaf(hh, wrv.y, acc[jc * 4 + 1]));
        acc[jc * 4 + 2] = fmaf(a, wlv.z, fmaf(hh, wrv.z, acc[jc * 4 + 2]));
        acc[jc * 4 + 3] = fmaf(a, wlv.w, fmaf(hh, wrv.w, acc[jc * 4 + 3]));
      }
    }
  }

#pragma unroll
  for (int jc = 0; jc < 16; ++jc) {
    if (do_relu) {
      acc[jc * 4 + 0] = fmaxf(acc[jc * 4 + 0], 0.f);
      acc[jc * 4 + 1] = fmaxf(acc[jc * 4 + 1], 0.f);
      acc[jc * 4 + 2] = fmaxf(acc[jc * 4 + 2], 0.f);
      acc[jc * 4 + 3] = fmaxf(acc[jc * 4 + 3], 0.f);
    }
  }
  if (hout) {
    float4* o4 = (float4*)(hout + (size_t)node * DHID);
#pragma unroll
    for (int jc = 0; jc < 16; ++jc) {
      float4 v;
      v.x = acc[jc * 4 + 0]; v.y = acc[jc * 4 + 1];
      v.z = acc[jc * 4 + 2]; v.w = acc[jc * 4 + 3];
      o4[jc] = v;
    }
  }
  if (hbout) {
    ushort4* ob = (ushort4*)(hbout + (size_t)node * DHID);
#pragma unroll
    for (int jc = 0; jc < 16; ++jc) {
      ushort4 bvu;
      bvu.x = f2bf(acc[jc * 4 + 0]); bvu.y = f2bf(acc[jc * 4 + 1]);
      bvu.z = f2bf(acc[jc * 4 + 2]); bvu.w = f2bf(acc[jc * 4 + 3]);
      ob[jc] = bvu;
    }
  }
}

// ---- Head: sort self-edges, logits, value, neighbors -----------------------

__global__ void k_head(const float* __restrict__ h, const int* __restrict__ dst,
                       const int* __restrict__ selfp, const int* __restrict__ selflist,
                       const int* __restrict__ selfcnt, const float* __restrict__ Wlog,
                       const float* __restrict__ blog, const float* __restrict__ Wval,
                       const float* __restrict__ bval, float* __restrict__ out) {
  __shared__ int sorted[SDEG];
  __shared__ int nbr[SDEG];
  int t = threadIdx.x;  // block = 64 threads (1 wave)
  int self = *selfp;
  if (t == 0) {
    int c = *selfcnt;
    if (c > SDEG) c = SDEG;
    int tmp[SDEG];
    for (int j = 0; j < SDEG; ++j) tmp[j] = (j < c) ? selflist[j] : 0;
    for (int a = 1; a < c; ++a) {
      int v = tmp[a];
      int bq = a - 1;
      while (bq >= 0 && tmp[bq] > v) { tmp[bq + 1] = tmp[bq]; --bq; }
      tmp[bq + 1] = v;
    }
    for (int j = 0; j < SDEG; ++j) sorted[j] = tmp[j];
  }
  __syncthreads();
  if (t < SDEG) nbr[t] = dst[sorted[t]];
  __syncthreads();

  int r = t >> 2, p = t & 3;
  float part = 0.f;
  for (int k = p * 32; k < p * 32 + 32; ++k) {
    float ev = (k < DHID) ? h[self * DHID + k] : h[nbr[r] * DHID + (k - DHID)];
    part += ev * Wlog[k];
  }
  part += __shfl_xor(part, 1);
  part += __shfl_xor(part, 2);
  if (p == 0) out[r] = part + blog[0];

  float pv = h[self * DHID + t] * Wval[t];
#pragma unroll
  for (int off = 32; off; off >>= 1) pv += __shfl_xor(pv, off);
  if (t == 0) out[SDEG] = pv + bval[0];

  if (t < SDEG) out[SDEG + 1 + t] = (float)nbr[t];
}

// ---- launcher --------------------------------------------------------------

extern "C" void kernel_launch(void* const* d_in, const int* in_sizes, int n_in,
                              void* d_out, int out_size, void* d_ws, size_t ws_size,
                              hipStream_t stream) {
  const float* x    = (const float*)d_in[0];
  const int*   ei   = (const int*)d_in[1];
  const int*   selfp= (const int*)d_in[2];
  const float* W0l  = (const float*)d_in[3];
  const float* W0r  = (const float*)d_in[4];
  const float* b0   = (const float*)d_in[5];
  const float* Wl   = (const float*)d_in[6];
  const float* Wr   = (const float*)d_in[7];
  const float* bb   = (const float*)d_in[8];
  const float* Wlog = (const float*)d_in[9];
  const float* blog = (const float*)d_in[10];
  const float* Wval = (const float*)d_in[11];
  const float* bval = (const float*)d_in[12];
  float* out = (float*)d_out;

  int N = in_sizes[0] / DIN;
  int E = in_sizes[1] / 2;
  int NB = (N + 63) >> BSH;
  const int* src = ei;
  const int* dstp = ei + E;

  size_t off = 0;
  auto alloc = [&](size_t bytes) {
    void* p = (char*)d_ws + off;
    off += (bytes + 255) & ~(size_t)255;
    return p;
  };
  int* meta    = (int*)alloc(64 * 4);            // [0]=selfcnt [1..16]=selflist
  int* hist    = (int*)alloc((size_t)NGRP * NB * 4);
  int* bbase   = (int*)alloc((size_t)(NB + 1) * 4);
  int* colsum  = (int*)alloc((size_t)NB * 4);
  int* ebuf    = (int*)alloc((size_t)E * 4);
  int* deg     = (int*)alloc((size_t)N * 4);
  int* rowptr  = (int*)alloc((size_t)N * 4);
  int* col     = (int*)alloc((size_t)E * 4);
  float* hF    = (float*)alloc((size_t)N * DHID * 4);          // final f32 h
  unsigned short* mb  = (unsigned short*)alloc((size_t)N * DHID * 2);
  unsigned short* hb0 = (unsigned short*)alloc((size_t)N * DHID * 2);
  unsigned short* hb1 = (unsigned short*)alloc((size_t)N * DHID * 2);
  unsigned short* hb2 = (unsigned short*)alloc((size_t)N * DHID * 2);
  int* selfcnt  = meta + 0;
  int* selflist = meta + 1;

  hipMemsetAsync(meta, 0, 64 * 4, stream);

  const int TB = 256;
  k_hist2<<<NGRP, TB, 0, stream>>>(dstp, hist, E, NB);
  k_scan2a<<<(NB + TB - 1) / TB, TB, 0, stream>>>(hist, colsum, NB);
  k_scan2b<<<1, 64, 0, stream>>>(colsum, bbase, NB);
  k_scatter2<<<NGRP, TB, 0, stream>>>(src, dstp, hist, bbase, ebuf, selfp,
                                      selfcnt, selflist, E, NB);
  k_bfill<<<NB, TB, 0, stream>>>(ebuf, bbase, rowptr, deg, col, N);

  k_layer0<<<2048, 256, 0, stream>>>(x, rowptr, deg, col, W0l, W0r, b0, hb0, N);

  int mm_grid = (N + 255) / 256;
  // layer 1: hb0 -> hb1 (relu)
  k_agg<<<2048, 256, 0, stream>>>(hb0, rowptr, deg, col, mb, N);
  k_mm<<<mm_grid, 256, 0, stream>>>(mb, hb0, Wl + 0 * 4096, Wr + 0 * 4096,
                                    bb + 0 * 64, (float*)nullptr, hb1, N, 1);
  // layer 2: hb1 -> hb2 (relu)
  k_agg<<<2048, 256, 0, stream>>>(hb1, rowptr, deg, col, mb, N);
  k_mm<<<mm_grid, 256, 0, stream>>>(mb, hb1, Wl + 1 * 4096, Wr + 1 * 4096,
                                    bb + 1 * 64, (float*)nullptr, hb2, N, 1);
  // layer 3: hb2 -> hF f32 (no relu)
  k_agg<<<2048, 256, 0, stream>>>(hb2, rowptr, deg, col, mb, N);
  k_mm<<<mm_grid, 256, 0, stream>>>(mb, hb2, Wl + 2 * 4096, Wr + 2 * 4096,
                                    bb + 2 * 64, hF, (unsigned short*)nullptr, N, 0);

  k_head<<<1, 64, 0, stream>>>(hF, dstp, selfp, selflist, selfcnt, Wlog, blog,
                               Wval, bval, out);
}

// Round 18
// 434.113 us; speedup vs baseline: 1.7177x; 1.1039x over previous
//
#include <hip/hip_runtime.h>

#define DHID 64
#define DIN 6
#define SDEG 16
#define BSH 6                 // bucket = dst >> 6 (64 nodes/bucket)
#define NBMAX 2048            // LDS histogram capacity (NB = 1563 for N=100k)
#define NGRP 128              // radix groups (WGs); chunk = E/NGRP ~ 12.5k edges

static __device__ __forceinline__ float rlane(float v, int k) {
  return __uint_as_float(__builtin_amdgcn_readlane(__float_as_uint(v), k));
}
static __device__ __forceinline__ unsigned short f2bf(float f) {  // RNE pack
  unsigned u = __float_as_uint(f);
  return (unsigned short)((u + 0x7fff + ((u >> 16) & 1)) >> 16);
}
static __device__ __forceinline__ float bf2f(unsigned short u) {
  return __uint_as_float((unsigned)u << 16);
}
static __device__ __forceinline__ float bflo(unsigned u) {  // low bf16 of a u32
  return __uint_as_float(u << 16);
}
static __device__ __forceinline__ float bfhi(unsigned u) {  // high bf16 of a u32
  return __uint_as_float(u & 0xffff0000u);
}

// ---- CSR build: per-WG-histogram radix sort (no global atomics) ------------

__global__ __launch_bounds__(256) void k_hist2(const int* __restrict__ dst,
                                               int* __restrict__ hist, int E, int NB) {
  __shared__ int h[NBMAX];
  int g = blockIdx.x;
  for (int i = threadIdx.x; i < NB; i += 256) h[i] = 0;
  __syncthreads();
  int chunk = (E + NGRP - 1) / NGRP;
  int e0 = g * chunk, e1 = min(E, e0 + chunk);
  for (int e = e0 + threadIdx.x; e < e1; e += 256)
    atomicAdd(&h[dst[e] >> BSH], 1);
  __syncthreads();
  for (int i = threadIdx.x; i < NB; i += 256)
    hist[(size_t)g * NB + i] = h[i];
}

__global__ __launch_bounds__(256) void k_scan2a(int* __restrict__ hist,
                                                int* __restrict__ colsum, int NB) {
  int b = blockIdx.x * 256 + threadIdx.x;
  if (b >= NB) return;
  int s = 0;
  for (int g = 0; g < NGRP; ++g) {
    size_t idx = (size_t)g * NB + b;
    int v = hist[idx];
    hist[idx] = s;
    s += v;
  }
  colsum[b] = s;
}

__global__ void k_scan2b(const int* __restrict__ colsum, int* __restrict__ bbase,
                         int NB) {
  int t = threadIdx.x;  // 64 threads
  int run = 0;
  for (int base = 0; base < NB; base += 64) {
    int i = base + t;
    int d = (i < NB) ? colsum[i] : 0;
    int v = d;
#pragma unroll
    for (int off = 1; off < 64; off <<= 1) {
      int u = __shfl_up(v, off);
      if (t >= off) v += u;
    }
    if (i < NB) bbase[i] = run + v - d;
    run += __shfl(v, 63);
  }
  if (t == 0) bbase[NB] = run;
}

__global__ __launch_bounds__(256) void k_scatter2(
    const int* __restrict__ src, const int* __restrict__ dst,
    const int* __restrict__ hist, const int* __restrict__ bbase,
    int* __restrict__ ebuf, const int* __restrict__ selfp,
    int* __restrict__ selfcnt, int* __restrict__ selflist, int E, int NB) {
  __shared__ int cur[NBMAX];
  int g = blockIdx.x;
  for (int i = threadIdx.x; i < NB; i += 256)
    cur[i] = hist[(size_t)g * NB + i] + bbase[i];
  __syncthreads();
  int self = *selfp;
  int chunk = (E + NGRP - 1) / NGRP;
  int e0 = g * chunk, e1 = min(E, e0 + chunk);
  for (int e = e0 + threadIdx.x; e < e1; e += 256) {
    int s = src[e], d = dst[e];
    int pos = atomicAdd(&cur[d >> BSH], 1);     // LDS atomic
    ebuf[pos] = (s << BSH) | (d & 63);
    if (s == self) {
      int i = atomicAdd(selfcnt, 1);
      if (i < SDEG) selflist[i] = e;
    }
  }
}

__global__ __launch_bounds__(256) void k_bfill(
    const int* __restrict__ ebuf, const int* __restrict__ bbase,
    int* __restrict__ rowptr, int* __restrict__ deg, int* __restrict__ col,
    int N) {
  __shared__ int cnt[64], cur[64];
  int b = blockIdx.x;
  int t = threadIdx.x;  // 256
  if (t < 64) cnt[t] = 0;
  __syncthreads();
  int lo = bbase[b], hi = bbase[b + 1];
  for (int i = lo + t; i < hi; i += 256) atomicAdd(&cnt[ebuf[i] & 63], 1);
  __syncthreads();
  if (t < 64) {
    int c = cnt[t];
    int v = c;
#pragma unroll
    for (int off = 1; off < 64; off <<= 1) {
      int u = __shfl_up(v, off);
      if (t >= off) v += u;
    }
    int start = lo + v - c;
    int node = (b << BSH) + t;
    if (node < N) { rowptr[node] = start; deg[node] = c; }
    cur[t] = start;
  }
  __syncthreads();
  for (int i = lo + t; i < hi; i += 256) {
    int p = ebuf[i];
    int pos = atomicAdd(&cur[p & 63], 1);
    col[pos] = p >> BSH;
  }
}

// ---- Layer 0: x[N,6] -> h[N,64] bf16, ReLU. 8-edge-grouped gather ----------
// 8 groups x 8 lanes: lane (eg,d8) loads dim d8 of edge eg's source row.
// 16 edges per 2 load instructions (vs 16). Cross-group reduce: 3 shfl_xor.

__global__ __launch_bounds__(256) void k_layer0(
    const float* __restrict__ x, const int* __restrict__ rowptr,
    const int* __restrict__ deg, const int* __restrict__ col,
    const float* __restrict__ W0l, const float* __restrict__ W0r,
    const float* __restrict__ b0, unsigned short* __restrict__ hbout, int N) {
  int lane = threadIdx.x & 63;
  int eg = lane >> 3;            // edge group 0..7
  int d8 = lane & 7;             // dim within group (d8 < 6 useful)
  int wid = blockIdx.x * (blockDim.x >> 6) + (threadIdx.x >> 6);
  int nw = gridDim.x * (blockDim.x >> 6);
  float w0l[DIN], w0r[DIN];
#pragma unroll
  for (int k = 0; k < DIN; ++k) {
    w0l[k] = W0l[k * DHID + lane];
    w0r[k] = W0r[k * DHID + lane];
  }
  float bv = b0[lane];
  int d6 = (lane < DIN) ? lane : 0;
  for (int node = wid; node < N; node += nw) {
    int start = rowptr[node], cnt = deg[node];
    float a = 0.f, a2 = 0.f;
    int e = 0;
    for (; e + 16 <= cnt; e += 16) {          // 2 loads cover 16 edges
      int s0 = col[start + e + eg];
      int s1 = col[start + e + 8 + eg];
      a  += (d8 < DIN) ? x[(size_t)s0 * DIN + d8] : 0.f;
      a2 += (d8 < DIN) ? x[(size_t)s1 * DIN + d8] : 0.f;
    }
    if (e + 8 <= cnt) {
      int s = col[start + e + eg];
      a += (d8 < DIN) ? x[(size_t)s * DIN + d8] : 0.f;
      e += 8;
    }
    int rem = cnt - e;
    if (eg < rem) {
      int s = col[start + e + eg];
      a += (d8 < DIN) ? x[(size_t)s * DIN + d8] : 0.f;
    }
    a += a2;
    a += __shfl_xor(a, 8);
    a += __shfl_xor(a, 16);
    a += __shfl_xor(a, 32);                   // every lane: sum for its d8 class
    float mean = a / fmaxf((float)cnt, 1.0f); // lane k (k<6) holds mean dim k
    float xi = x[(size_t)node * DIN + d6];
    float outv = bv;
#pragma unroll
    for (int k = 0; k < DIN; ++k) {
      outv = fmaf(rlane(mean, k), w0l[k], outv);
      outv = fmaf(rlane(xi, k), w0r[k], outv);
    }
    outv = fmaxf(outv, 0.f);
    hbout[(size_t)node * DHID + lane] = f2bf(outv);
  }
}

// ---- Aggregation, quad-edge: 4 edges per load instruction ------------------
// 4 groups x 16 lanes; each lane loads uint2 = 4 bf16 dims (16 lanes x 8B =
// full 128B row). 8 edges per 2 loads. Cross-group combine: shfl_xor(16,32);
// lanes 0-15 write packed uint2 (meanb layout unchanged).

__global__ __launch_bounds__(256) void k_agg(
    const unsigned short* __restrict__ hb, const int* __restrict__ rowptr,
    const int* __restrict__ deg, const int* __restrict__ col,
    unsigned short* __restrict__ meanb, int N) {
  int lane = threadIdx.x & 63;
  int qg = lane >> 4;            // edge slot within quad
  int l16 = lane & 15;           // uint2 index within row (dims 4*l16..+3)
  const uint2* hw = (const uint2*)hb;   // 16 uint2 per 64-dim bf16 row
  int wid = blockIdx.x * (blockDim.x >> 6) + (threadIdx.x >> 6);
  int nw = gridDim.x * (blockDim.x >> 6);
  for (int node = wid; node < N; node += nw) {
    int start = rowptr[node], cnt = deg[node];
    float a0 = 0.f, a1 = 0.f, a2 = 0.f, a3 = 0.f;
    float b0 = 0.f, b1 = 0.f, b2 = 0.f, b3 = 0.f;
    int e = 0;
    for (; e + 8 <= cnt; e += 8) {            // 2 loads cover 8 edges
      int s0 = col[start + e + qg];
      int s1 = col[start + e + 4 + qg];
      uint2 u0 = hw[(size_t)s0 * 16 + l16];
      uint2 u1 = hw[(size_t)s1 * 16 + l16];
      a0 += bflo(u0.x); a1 += bfhi(u0.x);
      a2 += bflo(u0.y); a3 += bfhi(u0.y);
      b0 += bflo(u1.x); b1 += bfhi(u1.x);
      b2 += bflo(u1.y); b3 += bfhi(u1.y);
    }
    if (e + 4 <= cnt) {
      int s = col[start + e + qg];
      uint2 u = hw[(size_t)s * 16 + l16];
      a0 += bflo(u.x); a1 += bfhi(u.x);
      a2 += bflo(u.y); a3 += bfhi(u.y);
      e += 4;
    }
    int rem = cnt - e;
    if (qg < rem) {
      int s = col[start + e + qg];
      uint2 u = hw[(size_t)s * 16 + l16];
      b0 += bflo(u.x); b1 += bfhi(u.x);
      b2 += bflo(u.y); b3 += bfhi(u.y);
    }
    a0 += b0; a1 += b1; a2 += b2; a3 += b3;
    a0 += __shfl_xor(a0, 16); a0 += __shfl_xor(a0, 32);
    a1 += __shfl_xor(a1, 16); a1 += __shfl_xor(a1, 32);
    a2 += __shfl_xor(a2, 16); a2 += __shfl_xor(a2, 32);
    a3 += __shfl_xor(a3, 16); a3 += __shfl_xor(a3, 32);
    if (qg == 0) {
      float inv = 1.0f / fmaxf((float)cnt, 1.0f);
      uint2 o;
      o.x = (unsigned)f2bf(a0 * inv) | ((unsigned)f2bf(a1 * inv) << 16);
      o.y = (unsigned)f2bf(a2 * inv) | ((unsigned)f2bf(a3 * inv) << 16);
      ((uint2*)meanb)[(size_t)node * 16 + l16] = o;
    }
  }
}

// ---- Transform: out = mean@Wl + h@Wr + b -----------------------------------
// Single pass, acc[64] resident (launch_bounds(256,2)); bf16 inputs.

__global__ __launch_bounds__(256, 2) void k_mm(
    const unsigned short* __restrict__ meanb,
    const unsigned short* __restrict__ hinb,
    const float* __restrict__ Wl, const float* __restrict__ Wr,
    const float* __restrict__ b, float* __restrict__ hout,
    unsigned short* __restrict__ hbout, int N, int do_relu) {
  __shared__ float4 sW[2064];  // [0..1023]=Wl rows, [1024..2047]=Wr, [2048..2063]=b
  int t = threadIdx.x;
  const float4* wl4 = (const float4*)Wl;
  const float4* wr4 = (const float4*)Wr;
  for (int i = t; i < 1024; i += 256) sW[i] = wl4[i];
  for (int i = t; i < 1024; i += 256) sW[1024 + i] = wr4[i];
  if (t < 16) sW[2048 + t] = ((const float4*)b)[t];
  __syncthreads();

  int node = blockIdx.x * 256 + t;
  if (node >= N) return;

  const uint4* m4 = (const uint4*)(meanb + (size_t)node * DHID);  // 8 bf16/uint4
  const uint4* h4 = (const uint4*)(hinb + (size_t)node * DHID);

  float acc[DHID];
#pragma unroll
  for (int jc = 0; jc < 16; ++jc) {
    float4 bv = sW[2048 + jc];
    acc[jc * 4 + 0] = bv.x; acc[jc * 4 + 1] = bv.y;
    acc[jc * 4 + 2] = bv.z; acc[jc * 4 + 3] = bv.w;
  }

  for (int kc = 0; kc < 8; ++kc) {     // 8 k-values per iteration
    uint4 mv = m4[kc];
    uint4 hv = h4[kc];
    float am[8], ah[8];
    am[0] = bflo(mv.x); am[1] = bfhi(mv.x);
    am[2] = bflo(mv.y); am[3] = bfhi(mv.y);
    am[4] = bflo(mv.z); am[5] = bfhi(mv.z);
    am[6] = bflo(mv.w); am[7] = bfhi(mv.w);
    ah[0] = bflo(hv.x); ah[1] = bfhi(hv.x);
    ah[2] = bflo(hv.y); ah[3] = bfhi(hv.y);
    ah[4] = bflo(hv.z); ah[5] = bfhi(hv.z);
    ah[6] = bflo(hv.w); ah[7] = bfhi(hv.w);
#pragma unroll
    for (int kk = 0; kk < 8; ++kk) {
      int k = kc * 8 + kk;
      float a = am[kk], hh = ah[kk];
#pragma unroll
      for (int jc = 0; jc < 16; ++jc) {
        float4 wlv = sW[k * 16 + jc];
        float4 wrv = sW[1024 + k * 16 + jc];
        acc[jc * 4 + 0] = fmaf(a, wlv.x, fmaf(hh, wrv.x, acc[jc * 4 + 0]));
        acc[jc * 4 + 1] = fmaf(a, wlv.y, fmaf(hh, wrv.y, acc[jc * 4 + 1]));
        acc[jc * 4 + 2] = fmaf(a, wlv.z, fmaf(hh, wrv.z, acc[jc * 4 + 2]));
        acc[jc * 4 + 3] = fmaf(a, wlv.w, fmaf(hh, wrv.w, acc[jc * 4 + 3]));
      }
    }
  }

#pragma unroll
  for (int jc = 0; jc < 16; ++jc) {
    if (do_relu) {
      acc[jc * 4 + 0] = fmaxf(acc[jc * 4 + 0], 0.f);
      acc[jc * 4 + 1] = fmaxf(acc[jc * 4 + 1], 0.f);
      acc[jc * 4 + 2] = fmaxf(acc[jc * 4 + 2], 0.f);
      acc[jc * 4 + 3] = fmaxf(acc[jc * 4 + 3], 0.f);
    }
  }
  if (hout) {
    float4* o4 = (float4*)(hout + (size_t)node * DHID);
#pragma unroll
    for (int jc = 0; jc < 16; ++jc) {
      float4 v;
      v.x = acc[jc * 4 + 0]; v.y = acc[jc * 4 + 1];
      v.z = acc[jc * 4 + 2]; v.w = acc[jc * 4 + 3];
      o4[jc] = v;
    }
  }
  if (hbout) {
    ushort4* ob = (ushort4*)(hbout + (size_t)node * DHID);
#pragma unroll
    for (int jc = 0; jc < 16; ++jc) {
      ushort4 bvu;
      bvu.x = f2bf(acc[jc * 4 + 0]); bvu.y = f2bf(acc[jc * 4 + 1]);
      bvu.z = f2bf(acc[jc * 4 + 2]); bvu.w = f2bf(acc[jc * 4 + 3]);
      ob[jc] = bvu;
    }
  }
}

// ---- Head: sort self-edges, logits, value, neighbors -----------------------

__global__ void k_head(const float* __restrict__ h, const int* __restrict__ dst,
                       const int* __restrict__ selfp, const int* __restrict__ selflist,
                       const int* __restrict__ selfcnt, const float* __restrict__ Wlog,
                       const float* __restrict__ blog, const float* __restrict__ Wval,
                       const float* __restrict__ bval, float* __restrict__ out) {
  __shared__ int sorted[SDEG];
  __shared__ int nbr[SDEG];
  int t = threadIdx.x;  // block = 64 threads (1 wave)
  int self = *selfp;
  if (t == 0) {
    int c = *selfcnt;
    if (c > SDEG) c = SDEG;
    int tmp[SDEG];
    for (int j = 0; j < SDEG; ++j) tmp[j] = (j < c) ? selflist[j] : 0;
    for (int a = 1; a < c; ++a) {
      int v = tmp[a];
      int bq = a - 1;
      while (bq >= 0 && tmp[bq] > v) { tmp[bq + 1] = tmp[bq]; --bq; }
      tmp[bq + 1] = v;
    }
    for (int j = 0; j < SDEG; ++j) sorted[j] = tmp[j];
  }
  __syncthreads();
  if (t < SDEG) nbr[t] = dst[sorted[t]];
  __syncthreads();

  int r = t >> 2, p = t & 3;
  float part = 0.f;
  for (int k = p * 32; k < p * 32 + 32; ++k) {
    float ev = (k < DHID) ? h[self * DHID + k] : h[nbr[r] * DHID + (k - DHID)];
    part += ev * Wlog[k];
  }
  part += __shfl_xor(part, 1);
  part += __shfl_xor(part, 2);
  if (p == 0) out[r] = part + blog[0];

  float pv = h[self * DHID + t] * Wval[t];
#pragma unroll
  for (int off = 32; off; off >>= 1) pv += __shfl_xor(pv, off);
  if (t == 0) out[SDEG] = pv + bval[0];

  if (t < SDEG) out[SDEG + 1 + t] = (float)nbr[t];
}

// ---- launcher --------------------------------------------------------------

extern "C" void kernel_launch(void* const* d_in, const int* in_sizes, int n_in,
                              void* d_out, int out_size, void* d_ws, size_t ws_size,
                              hipStream_t stream) {
  const float* x    = (const float*)d_in[0];
  const int*   ei   = (const int*)d_in[1];
  const int*   selfp= (const int*)d_in[2];
  const float* W0l  = (const float*)d_in[3];
  const float* W0r  = (const float*)d_in[4];
  const float* b0   = (const float*)d_in[5];
  const float* Wl   = (const float*)d_in[6];
  const float* Wr   = (const float*)d_in[7];
  const float* bb   = (const float*)d_in[8];
  const float* Wlog = (const float*)d_in[9];
  const float* blog = (const float*)d_in[10];
  const float* Wval = (const float*)d_in[11];
  const float* bval = (const float*)d_in[12];
  float* out = (float*)d_out;

  int N = in_sizes[0] / DIN;
  int E = in_sizes[1] / 2;
  int NB = (N + 63) >> BSH;
  const int* src = ei;
  const int* dstp = ei + E;

  size_t off = 0;
  auto alloc = [&](size_t bytes) {
    void* p = (char*)d_ws + off;
    off += (bytes + 255) & ~(size_t)255;
    return p;
  };
  int* meta    = (int*)alloc(64 * 4);            // [0]=selfcnt [1..16]=selflist
  int* hist    = (int*)alloc((size_t)NGRP * NB * 4);
  int* bbase   = (int*)alloc((size_t)(NB + 1) * 4);
  int* colsum  = (int*)alloc((size_t)NB * 4);
  int* ebuf    = (int*)alloc((size_t)E * 4);
  int* deg     = (int*)alloc((size_t)N * 4);
  int* rowptr  = (int*)alloc((size_t)N * 4);
  int* col     = (int*)alloc((size_t)E * 4);
  float* hF    = (float*)alloc((size_t)N * DHID * 4);          // final f32 h
  unsigned short* mb  = (unsigned short*)alloc((size_t)N * DHID * 2);
  unsigned short* hb0 = (unsigned short*)alloc((size_t)N * DHID * 2);
  unsigned short* hb1 = (unsigned short*)alloc((size_t)N * DHID * 2);
  unsigned short* hb2 = (unsigned short*)alloc((size_t)N * DHID * 2);
  int* selfcnt  = meta + 0;
  int* selflist = meta + 1;

  hipMemsetAsync(meta, 0, 64 * 4, stream);

  const int TB = 256;
  k_hist2<<<NGRP, TB, 0, stream>>>(dstp, hist, E, NB);
  k_scan2a<<<(NB + TB - 1) / TB, TB, 0, stream>>>(hist, colsum, NB);
  k_scan2b<<<1, 64, 0, stream>>>(colsum, bbase, NB);
  k_scatter2<<<NGRP, TB, 0, stream>>>(src, dstp, hist, bbase, ebuf, selfp,
                                      selfcnt, selflist, E, NB);
  k_bfill<<<NB, TB, 0, stream>>>(ebuf, bbase, rowptr, deg, col, N);

  k_layer0<<<2048, 256, 0, stream>>>(x, rowptr, deg, col, W0l, W0r, b0, hb0, N);

  int mm_grid = (N + 255) / 256;
  // layer 1: hb0 -> hb1 (relu)
  k_agg<<<2048, 256, 0, stream>>>(hb0, rowptr, deg, col, mb, N);
  k_mm<<<mm_grid, 256, 0, stream>>>(mb, hb0, Wl + 0 * 4096, Wr + 0 * 4096,
                                    bb + 0 * 64, (float*)nullptr, hb1, N, 1);
  // layer 2: hb1 -> hb2 (relu)
  k_agg<<<2048, 256, 0, stream>>>(hb1, rowptr, deg, col, mb, N);
  k_mm<<<mm_grid, 256, 0, stream>>>(mb, hb1, Wl + 1 * 4096, Wr + 1 * 4096,
                                    bb + 1 * 64, (float*)nullptr, hb2, N, 1);
  // layer 3: hb2 -> hF f32 (no relu)
  k_agg<<<2048, 256, 0, stream>>>(hb2, rowptr, deg, col, mb, N);
  k_mm<<<mm_grid, 256, 0, stream>>>(mb, hb2, Wl + 2 * 4096, Wr + 2 * 4096,
                                    bb + 2 * 64, hF, (unsigned short*)nullptr, N, 0);

  k_head<<<1, 64, 0, stream>>>(hF, dstp, selfp, selflist, selfcnt, Wlog, blog,
                               Wval, bval, out);
}